// Round 1
// baseline (328.374 us; speedup 1.0000x reference)
//
#include <hip/hip_runtime.h>
#include <cstdint>
#include <cstddef>

typedef __bf16 bf16;
typedef __bf16 bf16x8 __attribute__((ext_vector_type(8)));
typedef __bf16 bf16x4 __attribute__((ext_vector_type(4)));
typedef float  f32x4  __attribute__((ext_vector_type(4)));

#define DM     1024
#define MROWS  8192   // B*L
#define LSEQ   2048
#define NBATCH 4
#define NHEAD  16
#define BHEADS 64     // B*H
#define KV_S   8      // L-splits for KV partial reduction
#define KVT_STRIDE 4160  // 64*64 KV^T + 64 ksum

// async global->LDS, 16B per lane, LDS dest = wave-uniform base + lane*16
__device__ __forceinline__ void async16(const void* g, void* l) {
    __builtin_amdgcn_global_load_lds(
        (const __attribute__((address_space(1))) void*)g,
        (__attribute__((address_space(3))) void*)l, 16, 0, 0);
}

// ---------------- cast kernels (fp32 -> bf16) ----------------
__global__ __launch_bounds__(256) void cast3_kernel(
    const float* __restrict__ s0, const float* __restrict__ s1, const float* __restrict__ s2,
    bf16* __restrict__ d0, bf16* __restrict__ d1, bf16* __restrict__ d2) {
    const float* s = blockIdx.z == 0 ? s0 : (blockIdx.z == 1 ? s1 : s2);
    bf16*       d = blockIdx.z == 0 ? d0 : (blockIdx.z == 1 ? d1 : d2);
    const int i = blockIdx.x * 256 + threadIdx.x;
    float4 f = ((const float4*)s)[i];
    bf16x4 o; o[0] = (bf16)f.x; o[1] = (bf16)f.y; o[2] = (bf16)f.z; o[3] = (bf16)f.w;
    ((bf16x4*)d)[i] = o;
}

__global__ __launch_bounds__(256) void cast4_kernel(
    const float* __restrict__ s0, const float* __restrict__ s1,
    const float* __restrict__ s2, const float* __restrict__ s3,
    bf16* __restrict__ d0, bf16* __restrict__ d1, bf16* __restrict__ d2, bf16* __restrict__ d3) {
    const float* s = blockIdx.z == 0 ? s0 : (blockIdx.z == 1 ? s1 : (blockIdx.z == 2 ? s2 : s3));
    bf16*       d = blockIdx.z == 0 ? d0 : (blockIdx.z == 1 ? d1 : (blockIdx.z == 2 ? d2 : d3));
    const int i = blockIdx.x * 256 + threadIdx.x;
    float4 f = ((const float4*)s)[i];
    bf16x4 o; o[0] = (bf16)f.x; o[1] = (bf16)f.y; o[2] = (bf16)f.z; o[3] = (bf16)f.w;
    ((bf16x4*)d)[i] = o;
}

// ---------------- batched NT GEMM: C = A @ B^T ----------------
// A [M x K] bf16 row-major, B [N x K] bf16 row-major.
// mode 0: store bf16; mode 1: fmap (elu+1) then store bf16; mode 2: store fp32
struct GemmArgs {
    const bf16* A[3];
    const bf16* B[3];
    void*       C[3];
    int         mode[3];
    int         Ndim;
    int         Kdim;
};

__global__ __launch_bounds__(256) void gemm_nt(GemmArgs args) {
    const int z = blockIdx.z;
    const bf16* __restrict__ A  = args.A[z];
    const bf16* __restrict__ Bm = args.B[z];
    void* Cp = args.C[z];
    const int mode = args.mode[z];
    const int N = args.Ndim, K = args.Kdim;

    __shared__ __attribute__((aligned(16))) bf16 sA[128 * 32];
    __shared__ __attribute__((aligned(16))) bf16 sB[128 * 32];

    const int tid  = threadIdx.x;
    const int wave = tid >> 6;
    const int lane = tid & 63;
    const int wm = wave >> 1, wn = wave & 1;
    const int row0 = blockIdx.y * 128;
    const int col0 = blockIdx.x * 128;

    // staging: per wave 2 issues of 16 rows (64B/row = 4 lanes x 16B)
    const int sr = lane >> 2;         // row within 16-row issue
    const int sc = (lane & 3) * 8;    // element offset (16B chunks)
    const bf16* gA = A  + (size_t)(row0 + wave * 32 + sr) * K + sc;
    const bf16* gB = Bm + (size_t)(col0 + wave * 32 + sr) * K + sc;
    bf16* lA = &sA[(wave * 32) * 32];
    bf16* lB = &sB[(wave * 32) * 32];

    f32x4 acc[4][4] = {};

    const int lr = lane & 15;
    const int lk = (lane >> 4) * 8;

    for (int k0 = 0; k0 < K; k0 += 32) {
        async16(gA + k0,                 lA);
        async16(gA + k0 + 16 * (size_t)K, lA + 16 * 32);
        async16(gB + k0,                 lB);
        async16(gB + k0 + 16 * (size_t)K, lB + 16 * 32);
        __syncthreads();

        bf16x8 af[4], bfr[4];
        #pragma unroll
        for (int mi = 0; mi < 4; ++mi)
            af[mi] = *(const bf16x8*)&sA[(wm * 64 + mi * 16 + lr) * 32 + lk];
        #pragma unroll
        for (int ni = 0; ni < 4; ++ni)
            bfr[ni] = *(const bf16x8*)&sB[(wn * 64 + ni * 16 + lr) * 32 + lk];
        #pragma unroll
        for (int mi = 0; mi < 4; ++mi)
            #pragma unroll
            for (int ni = 0; ni < 4; ++ni)
                acc[mi][ni] = __builtin_amdgcn_mfma_f32_16x16x32_bf16(af[mi], bfr[ni], acc[mi][ni], 0, 0, 0);
        __syncthreads();
    }

    const int qd = lane >> 4;
    #pragma unroll
    for (int mi = 0; mi < 4; ++mi) {
        #pragma unroll
        for (int ni = 0; ni < 4; ++ni) {
            #pragma unroll
            for (int r = 0; r < 4; ++r) {
                const int grow = row0 + wm * 64 + mi * 16 + qd * 4 + r;
                const int gcol = col0 + wn * 64 + ni * 16 + lr;
                float val = acc[mi][ni][r];
                if (mode == 1) val = (val > 0.f) ? (val + 1.f) : __expf(val);
                if (mode == 2) ((float*)Cp)[(size_t)grow * N + gcol] = val;
                else           ((bf16*)Cp)[(size_t)grow * N + gcol] = (bf16)val;
            }
        }
    }
}

// ---------------- KV^T partial: KVT[m][d] += V[n,m]*K[n,d], plus Ksum ----------------
__global__ __launch_bounds__(256) void kv_partial(const bf16* __restrict__ Kp,
                                                  const bf16* __restrict__ Vp,
                                                  float* __restrict__ KVTp) {
    const int bh = blockIdx.x, s = blockIdx.y;
    const int b = bh >> 4, h = bh & 15;
    const int tid = threadIdx.x;
    const int m  = tid & 63;   // KVT row (V column); for wave 0 also serves as d for ksum
    const int dg = tid >> 6;   // d-group (= wave index)

    __shared__ float sK[32][64];
    __shared__ float sV[32][64];

    float acc[16] = {};
    float ks = 0.f;

    const int rr = tid >> 3;          // 0..31 row
    const int cc = (tid & 7) * 8;     // element offset

    const size_t rowbase = (size_t)(b * LSEQ + s * 256) * DM + h * 64;

    for (int c = 0; c < 8; ++c) {
        {
            const size_t g = rowbase + (size_t)(c * 32 + rr) * DM + cc;
            bf16x8 k8 = *(const bf16x8*)&Kp[g];
            bf16x8 v8 = *(const bf16x8*)&Vp[g];
            float4 kf0 = {(float)k8[0], (float)k8[1], (float)k8[2], (float)k8[3]};
            float4 kf1 = {(float)k8[4], (float)k8[5], (float)k8[6], (float)k8[7]};
            float4 vf0 = {(float)v8[0], (float)v8[1], (float)v8[2], (float)v8[3]};
            float4 vf1 = {(float)v8[4], (float)v8[5], (float)v8[6], (float)v8[7]};
            *(float4*)&sK[rr][cc]     = kf0;
            *(float4*)&sK[rr][cc + 4] = kf1;
            *(float4*)&sV[rr][cc]     = vf0;
            *(float4*)&sV[rr][cc + 4] = vf1;
        }
        __syncthreads();
        #pragma unroll 4
        for (int n = 0; n < 32; ++n) {
            const float vv = sV[n][m];
            const float4* pk = (const float4*)&sK[n][dg * 16];
            #pragma unroll
            for (int t4 = 0; t4 < 4; ++t4) {
                float4 kk = pk[t4];
                acc[t4 * 4 + 0] += vv * kk.x;
                acc[t4 * 4 + 1] += vv * kk.y;
                acc[t4 * 4 + 2] += vv * kk.z;
                acc[t4 * 4 + 3] += vv * kk.w;
            }
            if (dg == 0) ks += sK[n][m];
        }
        __syncthreads();
    }

    float* outp = &KVTp[(size_t)(bh * KV_S + s) * KVT_STRIDE];
    #pragma unroll
    for (int t4 = 0; t4 < 4; ++t4) {
        float4 o = {acc[t4 * 4 + 0], acc[t4 * 4 + 1], acc[t4 * 4 + 2], acc[t4 * 4 + 3]};
        *(float4*)&outp[m * 64 + dg * 16 + t4 * 4] = o;
    }
    if (dg == 0) outp[4096 + m] = ks;
}

__global__ __launch_bounds__(256) void kv_reduce(const float* __restrict__ KVTp,
                                                 bf16* __restrict__ KVT,
                                                 float* __restrict__ Ksum) {
    const int bh = blockIdx.x;
    for (int idx = threadIdx.x; idx < KVT_STRIDE; idx += 256) {
        float s = 0.f;
        #pragma unroll
        for (int p = 0; p < KV_S; ++p) s += KVTp[(size_t)(bh * KV_S + p) * KVT_STRIDE + idx];
        if (idx < 4096) KVT[(size_t)bh * 4096 + idx] = (bf16)s;
        else            Ksum[bh * 64 + (idx - 4096)] = s;
    }
}

// ---------------- Z[n] = 1/(Q[n,:].Ksum + eps) ----------------
__global__ __launch_bounds__(256) void z_kernel(const bf16* __restrict__ Qp,
                                                const float* __restrict__ Ksum,
                                                float* __restrict__ Z) {
    const int bh = blockIdx.x;
    const int b = bh >> 4, h = bh & 15;
    const int n = blockIdx.y * 256 + threadIdx.x;
    __shared__ float sks[64];
    if (threadIdx.x < 64) sks[threadIdx.x] = Ksum[bh * 64 + threadIdx.x];
    __syncthreads();
    const bf16* qrow = &Qp[(size_t)(b * LSEQ + n) * DM + h * 64];
    float acc = 0.f;
    #pragma unroll
    for (int c = 0; c < 8; ++c) {
        bf16x8 q8 = *(const bf16x8*)&qrow[c * 8];
        #pragma unroll
        for (int j = 0; j < 8; ++j) acc += (float)q8[j] * sks[c * 8 + j];
    }
    Z[(size_t)bh * LSEQ + n] = 1.0f / (acc + 1e-8f);
}

// ---------------- attn out: A[n, h*64+m] = Z[n] * sum_d Q[n,d]*KVT[m,d] (MFMA NT) ----------------
__global__ __launch_bounds__(256) void attn_out(const bf16* __restrict__ Qp,
                                                const bf16* __restrict__ KVT,
                                                const float* __restrict__ Z,
                                                bf16* __restrict__ Ab) {
    const int bh = blockIdx.y;
    const int b = bh >> 4, h = bh & 15;
    const int row0 = blockIdx.x * 128;
    const int tid = threadIdx.x, wave = tid >> 6, lane = tid & 63;

    __shared__ __attribute__((aligned(16))) bf16 sQ[128 * 64];
    __shared__ __attribute__((aligned(16))) bf16 sKV[64 * 64];

    const bf16* qbase = &Qp[(size_t)(b * LSEQ + row0) * DM + h * 64];
    #pragma unroll
    for (int j = 0; j < 4; ++j) {   // 8 rows (128B each) per issue
        const int r0 = wave * 32 + j * 8;
        async16(qbase + (size_t)(r0 + (lane >> 3)) * DM + (lane & 7) * 8, &sQ[r0 * 64]);
    }
    const bf16* kvbase = &KVT[(size_t)bh * 4096];
    #pragma unroll
    for (int j = 0; j < 2; ++j) {
        const int r0 = wave * 16 + j * 8;
        async16(kvbase + (r0 + (lane >> 3)) * 64 + (lane & 7) * 8, &sKV[r0 * 64]);
    }
    __syncthreads();

    f32x4 acc[2][4] = {};
    const int lr = lane & 15, qd = lane >> 4;
    #pragma unroll
    for (int ks = 0; ks < 2; ++ks) {
        bf16x8 af[2], bfr[4];
        #pragma unroll
        for (int mi = 0; mi < 2; ++mi)
            af[mi] = *(const bf16x8*)&sQ[(wave * 32 + mi * 16 + lr) * 64 + ks * 32 + qd * 8];
        #pragma unroll
        for (int ni = 0; ni < 4; ++ni)
            bfr[ni] = *(const bf16x8*)&sKV[(ni * 16 + lr) * 64 + ks * 32 + qd * 8];
        #pragma unroll
        for (int mi = 0; mi < 2; ++mi)
            #pragma unroll
            for (int ni = 0; ni < 4; ++ni)
                acc[mi][ni] = __builtin_amdgcn_mfma_f32_16x16x32_bf16(af[mi], bfr[ni], acc[mi][ni], 0, 0, 0);
    }

    #pragma unroll
    for (int mi = 0; mi < 2; ++mi) {
        #pragma unroll
        for (int rr = 0; rr < 4; ++rr) {
            const int nrow = row0 + wave * 32 + mi * 16 + qd * 4 + rr;
            const float zv = Z[(size_t)bh * LSEQ + nrow];
            #pragma unroll
            for (int ni = 0; ni < 4; ++ni)
                Ab[(size_t)(b * LSEQ + nrow) * DM + h * 64 + ni * 16 + lr] =
                    (bf16)(acc[mi][ni][rr] * zv);
        }
    }
}

extern "C" void kernel_launch(void* const* d_in, const int* in_sizes, int n_in,
                              void* d_out, int out_size, void* d_ws, size_t ws_size,
                              hipStream_t stream) {
    const float* q  = (const float*)d_in[0];
    const float* k  = (const float*)d_in[1];
    const float* v  = (const float*)d_in[2];
    // d_in[3] = mask (all-ones, unused in linear branch)
    const float* wq = (const float*)d_in[4];
    const float* wk = (const float*)d_in[5];
    const float* wv = (const float*)d_in[6];
    const float* wo = (const float*)d_in[7];

    char* ws = (char*)d_ws;
    size_t off = 0;
    auto alloc = [&](size_t bytes) -> void* {
        void* p = ws + off;
        off += (bytes + 255) & ~(size_t)255;
        return p;
    };

    bf16* qb   = (bf16*)alloc((size_t)MROWS * DM * 2);
    bf16* kb   = (bf16*)alloc((size_t)MROWS * DM * 2);
    bf16* vb   = (bf16*)alloc((size_t)MROWS * DM * 2);
    bf16* wqb  = (bf16*)alloc((size_t)DM * DM * 2);
    bf16* wkb  = (bf16*)alloc((size_t)DM * DM * 2);
    bf16* wvb  = (bf16*)alloc((size_t)DM * DM * 2);
    bf16* wob  = (bf16*)alloc((size_t)DM * DM * 2);
    bf16* Qp   = (bf16*)alloc((size_t)MROWS * DM * 2);
    bf16* Kp   = (bf16*)alloc((size_t)MROWS * DM * 2);
    bf16* Vp   = (bf16*)alloc((size_t)MROWS * DM * 2);
    bf16* Ab   = (bf16*)alloc((size_t)MROWS * DM * 2);
    float* KVTp = (float*)alloc((size_t)BHEADS * KV_S * KVT_STRIDE * 4);
    bf16* KVT  = (bf16*)alloc((size_t)BHEADS * 4096 * 2);
    float* Ksum = (float*)alloc((size_t)BHEADS * 64 * 4);
    float* Z    = (float*)alloc((size_t)BHEADS * LSEQ * 4);

    // 1. casts
    cast3_kernel<<<dim3(MROWS * DM / 4 / 256, 1, 3), 256, 0, stream>>>(q, k, v, qb, kb, vb);
    cast4_kernel<<<dim3(DM * DM / 4 / 256, 1, 4), 256, 0, stream>>>(wq, wk, wv, wo, wqb, wkb, wvb, wob);

    // 2. projections (fused fmap for Q,K)
    GemmArgs pa;
    pa.A[0] = qb;  pa.A[1] = kb;  pa.A[2] = vb;
    pa.B[0] = wqb; pa.B[1] = wkb; pa.B[2] = wvb;
    pa.C[0] = Qp;  pa.C[1] = Kp;  pa.C[2] = Vp;
    pa.mode[0] = 1; pa.mode[1] = 1; pa.mode[2] = 0;
    pa.Ndim = DM; pa.Kdim = DM;
    gemm_nt<<<dim3(DM / 128, MROWS / 128, 3), 256, 0, stream>>>(pa);

    // 3. KV^T + Ksum
    kv_partial<<<dim3(BHEADS, KV_S), 256, 0, stream>>>(Kp, Vp, KVTp);
    kv_reduce<<<dim3(BHEADS), 256, 0, stream>>>(KVTp, KVT, Ksum);

    // 4. Z
    z_kernel<<<dim3(BHEADS, LSEQ / 256), 256, 0, stream>>>(Qp, Ksum, Z);

    // 5. attention output (Z fused into epilogue)
    attn_out<<<dim3(LSEQ / 128, BHEADS), 256, 0, stream>>>(Qp, KVT, Z, Ab);

    // 6. output projection -> fp32 d_out
    GemmArgs fa;
    fa.A[0] = Ab; fa.A[1] = nullptr; fa.A[2] = nullptr;
    fa.B[0] = wob; fa.B[1] = nullptr; fa.B[2] = nullptr;
    fa.C[0] = d_out; fa.C[1] = nullptr; fa.C[2] = nullptr;
    fa.mode[0] = 2; fa.mode[1] = 0; fa.mode[2] = 0;
    fa.Ndim = DM; fa.Kdim = DM;
    gemm_nt<<<dim3(DM / 128, MROWS / 128, 1), 256, 0, stream>>>(fa);
}

// Round 2
// 314.875 us; speedup vs baseline: 1.0429x; 1.0429x over previous
//
#include <hip/hip_runtime.h>
#include <cstdint>
#include <cstddef>

typedef __bf16 bf16;
typedef __bf16 bf16x8 __attribute__((ext_vector_type(8)));
typedef __bf16 bf16x4 __attribute__((ext_vector_type(4)));
typedef float  f32x4  __attribute__((ext_vector_type(4)));

#define DM     1024
#define MROWS  8192   // B*L
#define LSEQ   2048
#define NBATCH 4
#define NHEAD  16
#define BHEADS 64     // B*H
#define KV_S   8      // L-splits for KV partial reduction
#define KVT_STRIDE 4160  // 64*64 KV^T + 64 ksum

// async global->LDS, 16B per lane, LDS dest = wave-uniform base + lane*16
__device__ __forceinline__ void async16(const void* g, void* l) {
    __builtin_amdgcn_global_load_lds(
        (const __attribute__((address_space(1))) void*)g,
        (__attribute__((address_space(3))) void*)l, 16, 0, 0);
}

// ---------------- merged cast kernel (fp32 -> bf16), 7 tensors ----------------
struct CastArgs {
    const float* s[7];
    bf16*        d[7];
    int          nblk[7];
};

__global__ __launch_bounds__(256) void cast_all(CastArgs a) {
    const int z = blockIdx.z;
    if ((int)blockIdx.x >= a.nblk[z]) return;
    const int i = blockIdx.x * 256 + threadIdx.x;
    float4 f = ((const float4*)a.s[z])[i];
    bf16x4 o; o[0] = (bf16)f.x; o[1] = (bf16)f.y; o[2] = (bf16)f.z; o[3] = (bf16)f.w;
    ((bf16x4*)a.d[z])[i] = o;
}

// ---------------- batched NT GEMM: C = A @ B^T ----------------
// A [M x K] bf16 row-major, B [N x K] bf16 row-major. BK=64, XOR-swizzled LDS.
// mode 0: store bf16; mode 1: fmap (elu+1) then store bf16; mode 2: store fp32
struct GemmArgs {
    const bf16* A[3];
    const bf16* B[3];
    void*       C[3];
    int         mode[3];
    int         Ndim;
    int         Kdim;
};

__global__ __launch_bounds__(256) void gemm_nt(GemmArgs args) {
    const int z = blockIdx.z;
    const bf16* __restrict__ A  = args.A[z];
    const bf16* __restrict__ Bm = args.B[z];
    void* Cp = args.C[z];
    const int mode = args.mode[z];
    const int N = args.Ndim, K = args.Kdim;

    __shared__ __attribute__((aligned(16))) bf16 sA[128 * 64];
    __shared__ __attribute__((aligned(16))) bf16 sB[128 * 64];

    const int tid  = threadIdx.x;
    const int wave = tid >> 6;
    const int lane = tid & 63;
    const int wm = wave >> 1, wn = wave & 1;
    const int row0 = blockIdx.y * 128;
    const int col0 = blockIdx.x * 128;

    // staging: 8 rows x 8 chunks (16B) per issue per wave; chunk XOR-swizzled by row&7
    const int rr = lane >> 3;          // row within 8-row issue
    const int cc = lane & 7;           // 16B chunk index
    const int csw = ((cc ^ rr) * 8);   // swizzled element offset within 64-col row
    const bf16* gA = A  + (size_t)(row0 + wave * 32 + rr) * K + csw;
    const bf16* gB = Bm + (size_t)(col0 + wave * 32 + rr) * K + csw;

    f32x4 acc[4][4] = {};

    const int lr = lane & 15;
    const int qd = lane >> 4;
    const int swz = lr & 7;

    for (int k0 = 0; k0 < K; k0 += 64) {
        #pragma unroll
        for (int j = 0; j < 4; ++j) {
            async16(gA + k0 + (size_t)(j * 8) * K, &sA[(wave * 32 + j * 8) * 64]);
            async16(gB + k0 + (size_t)(j * 8) * K, &sB[(wave * 32 + j * 8) * 64]);
        }
        __syncthreads();

        #pragma unroll
        for (int ks = 0; ks < 2; ++ks) {
            bf16x8 af[4], bfr[4];
            #pragma unroll
            for (int mi = 0; mi < 4; ++mi)
                af[mi] = *(const bf16x8*)&sA[(wm * 64 + mi * 16 + lr) * 64 + (((ks * 4 + qd) ^ swz) * 8)];
            #pragma unroll
            for (int ni = 0; ni < 4; ++ni)
                bfr[ni] = *(const bf16x8*)&sB[(wn * 64 + ni * 16 + lr) * 64 + (((ks * 4 + qd) ^ swz) * 8)];
            #pragma unroll
            for (int mi = 0; mi < 4; ++mi)
                #pragma unroll
                for (int ni = 0; ni < 4; ++ni)
                    acc[mi][ni] = __builtin_amdgcn_mfma_f32_16x16x32_bf16(af[mi], bfr[ni], acc[mi][ni], 0, 0, 0);
        }
        __syncthreads();
    }

    #pragma unroll
    for (int mi = 0; mi < 4; ++mi) {
        #pragma unroll
        for (int ni = 0; ni < 4; ++ni) {
            #pragma unroll
            for (int r = 0; r < 4; ++r) {
                const int grow = row0 + wm * 64 + mi * 16 + qd * 4 + r;
                const int gcol = col0 + wn * 64 + ni * 16 + lr;
                float val = acc[mi][ni][r];
                if (mode == 1) val = (val > 0.f) ? (val + 1.f) : __expf(val);
                if (mode == 2) ((float*)Cp)[(size_t)grow * N + gcol] = val;
                else           ((bf16*)Cp)[(size_t)grow * N + gcol] = (bf16)val;
            }
        }
    }
}

// ---------------- KV^T partial: KVT[m][d] += V[n,m]*K[n,d], plus Ksum ----------------
__global__ __launch_bounds__(256) void kv_partial(const bf16* __restrict__ Kp,
                                                  const bf16* __restrict__ Vp,
                                                  float* __restrict__ KVTp) {
    const int bh = blockIdx.x, s = blockIdx.y;
    const int b = bh >> 4, h = bh & 15;
    const int tid = threadIdx.x;
    const int m  = tid & 63;   // KVT row (V column); for wave 0 also serves as d for ksum
    const int dg = tid >> 6;   // d-group (= wave index)

    __shared__ float sK[32][64];
    __shared__ float sV[32][64];

    float acc[16] = {};
    float ks = 0.f;

    const int rr = tid >> 3;          // 0..31 row
    const int cc = (tid & 7) * 8;     // element offset

    const size_t rowbase = (size_t)(b * LSEQ + s * 256) * DM + h * 64;

    for (int c = 0; c < 8; ++c) {
        {
            const size_t g = rowbase + (size_t)(c * 32 + rr) * DM + cc;
            bf16x8 k8 = *(const bf16x8*)&Kp[g];
            bf16x8 v8 = *(const bf16x8*)&Vp[g];
            float4 kf0 = {(float)k8[0], (float)k8[1], (float)k8[2], (float)k8[3]};
            float4 kf1 = {(float)k8[4], (float)k8[5], (float)k8[6], (float)k8[7]};
            float4 vf0 = {(float)v8[0], (float)v8[1], (float)v8[2], (float)v8[3]};
            float4 vf1 = {(float)v8[4], (float)v8[5], (float)v8[6], (float)v8[7]};
            *(float4*)&sK[rr][cc]     = kf0;
            *(float4*)&sK[rr][cc + 4] = kf1;
            *(float4*)&sV[rr][cc]     = vf0;
            *(float4*)&sV[rr][cc + 4] = vf1;
        }
        __syncthreads();
        #pragma unroll 4
        for (int n = 0; n < 32; ++n) {
            const float vv = sV[n][m];
            const float4* pk = (const float4*)&sK[n][dg * 16];
            #pragma unroll
            for (int t4 = 0; t4 < 4; ++t4) {
                float4 kk = pk[t4];
                acc[t4 * 4 + 0] += vv * kk.x;
                acc[t4 * 4 + 1] += vv * kk.y;
                acc[t4 * 4 + 2] += vv * kk.z;
                acc[t4 * 4 + 3] += vv * kk.w;
            }
            if (dg == 0) ks += sK[n][m];
        }
        __syncthreads();
    }

    float* outp = &KVTp[(size_t)(bh * KV_S + s) * KVT_STRIDE];
    #pragma unroll
    for (int t4 = 0; t4 < 4; ++t4) {
        float4 o = {acc[t4 * 4 + 0], acc[t4 * 4 + 1], acc[t4 * 4 + 2], acc[t4 * 4 + 3]};
        *(float4*)&outp[m * 64 + dg * 16 + t4 * 4] = o;
    }
    if (dg == 0) outp[4096 + m] = ks;
}

// parallel reduce: grid (BHEADS, 17)
__global__ __launch_bounds__(256) void kv_reduce(const float* __restrict__ KVTp,
                                                 bf16* __restrict__ KVT,
                                                 float* __restrict__ Ksum) {
    const int bh = blockIdx.x;
    const int idx = blockIdx.y * 256 + threadIdx.x;
    if (idx >= KVT_STRIDE) return;
    float s = 0.f;
    #pragma unroll
    for (int p = 0; p < KV_S; ++p) s += KVTp[(size_t)(bh * KV_S + p) * KVT_STRIDE + idx];
    if (idx < 4096) KVT[(size_t)bh * 4096 + idx] = (bf16)s;
    else            Ksum[bh * 64 + (idx - 4096)] = s;
}

// ---------------- Z[n] = 1/(Q[n,:].Ksum + eps) ----------------
__global__ __launch_bounds__(256) void z_kernel(const bf16* __restrict__ Qp,
                                                const float* __restrict__ Ksum,
                                                float* __restrict__ Z) {
    const int bh = blockIdx.x;
    const int b = bh >> 4, h = bh & 15;
    const int n = blockIdx.y * 256 + threadIdx.x;
    __shared__ float sks[64];
    if (threadIdx.x < 64) sks[threadIdx.x] = Ksum[bh * 64 + threadIdx.x];
    __syncthreads();
    const bf16* qrow = &Qp[(size_t)(b * LSEQ + n) * DM + h * 64];
    float acc = 0.f;
    #pragma unroll
    for (int c = 0; c < 8; ++c) {
        bf16x8 q8 = *(const bf16x8*)&qrow[c * 8];
        #pragma unroll
        for (int j = 0; j < 8; ++j) acc += (float)q8[j] * sks[c * 8 + j];
    }
    Z[(size_t)bh * LSEQ + n] = 1.0f / (acc + 1e-8f);
}

// ---------------- attn out: A[n, h*64+m] = Z[n] * sum_d Q[n,d]*KVT[m,d] (MFMA NT) ----------------
__global__ __launch_bounds__(256) void attn_out(const bf16* __restrict__ Qp,
                                                const bf16* __restrict__ KVT,
                                                const float* __restrict__ Z,
                                                bf16* __restrict__ Ab) {
    const int bh = blockIdx.y;
    const int b = bh >> 4, h = bh & 15;
    const int row0 = blockIdx.x * 128;
    const int tid = threadIdx.x, wave = tid >> 6, lane = tid & 63;

    __shared__ __attribute__((aligned(16))) bf16 sQ[128 * 64];
    __shared__ __attribute__((aligned(16))) bf16 sKV[64 * 64];

    const bf16* qbase = &Qp[(size_t)(b * LSEQ + row0) * DM + h * 64];
    #pragma unroll
    for (int j = 0; j < 4; ++j) {   // 8 rows (128B each) per issue
        const int r0 = wave * 32 + j * 8;
        async16(qbase + (size_t)(r0 + (lane >> 3)) * DM + (lane & 7) * 8, &sQ[r0 * 64]);
    }
    const bf16* kvbase = &KVT[(size_t)bh * 4096];
    #pragma unroll
    for (int j = 0; j < 2; ++j) {
        const int r0 = wave * 16 + j * 8;
        async16(kvbase + (r0 + (lane >> 3)) * 64 + (lane & 7) * 8, &sKV[r0 * 64]);
    }
    __syncthreads();

    f32x4 acc[2][4] = {};
    const int lr = lane & 15, qd = lane >> 4;
    #pragma unroll
    for (int ks = 0; ks < 2; ++ks) {
        bf16x8 af[2], bfr[4];
        #pragma unroll
        for (int mi = 0; mi < 2; ++mi)
            af[mi] = *(const bf16x8*)&sQ[(wave * 32 + mi * 16 + lr) * 64 + ks * 32 + qd * 8];
        #pragma unroll
        for (int ni = 0; ni < 4; ++ni)
            bfr[ni] = *(const bf16x8*)&sKV[(ni * 16 + lr) * 64 + ks * 32 + qd * 8];
        #pragma unroll
        for (int mi = 0; mi < 2; ++mi)
            #pragma unroll
            for (int ni = 0; ni < 4; ++ni)
                acc[mi][ni] = __builtin_amdgcn_mfma_f32_16x16x32_bf16(af[mi], bfr[ni], acc[mi][ni], 0, 0, 0);
    }

    #pragma unroll
    for (int mi = 0; mi < 2; ++mi) {
        #pragma unroll
        for (int rr = 0; rr < 4; ++rr) {
            const int nrow = row0 + wave * 32 + mi * 16 + qd * 4 + rr;
            const float zv = Z[(size_t)bh * LSEQ + nrow];
            #pragma unroll
            for (int ni = 0; ni < 4; ++ni)
                Ab[(size_t)(b * LSEQ + nrow) * DM + h * 64 + ni * 16 + lr] =
                    (bf16)(acc[mi][ni][rr] * zv);
        }
    }
}

extern "C" void kernel_launch(void* const* d_in, const int* in_sizes, int n_in,
                              void* d_out, int out_size, void* d_ws, size_t ws_size,
                              hipStream_t stream) {
    const float* q  = (const float*)d_in[0];
    const float* k  = (const float*)d_in[1];
    const float* v  = (const float*)d_in[2];
    // d_in[3] = mask (all-ones, unused in linear branch)
    const float* wq = (const float*)d_in[4];
    const float* wk = (const float*)d_in[5];
    const float* wv = (const float*)d_in[6];
    const float* wo = (const float*)d_in[7];

    char* ws = (char*)d_ws;
    size_t off = 0;
    auto alloc = [&](size_t bytes) -> void* {
        void* p = ws + off;
        off += (bytes + 255) & ~(size_t)255;
        return p;
    };

    bf16* qb   = (bf16*)alloc((size_t)MROWS * DM * 2);
    bf16* kb   = (bf16*)alloc((size_t)MROWS * DM * 2);
    bf16* vb   = (bf16*)alloc((size_t)MROWS * DM * 2);
    bf16* wqb  = (bf16*)alloc((size_t)DM * DM * 2);
    bf16* wkb  = (bf16*)alloc((size_t)DM * DM * 2);
    bf16* wvb  = (bf16*)alloc((size_t)DM * DM * 2);
    bf16* wob  = (bf16*)alloc((size_t)DM * DM * 2);
    bf16* Qp   = (bf16*)alloc((size_t)MROWS * DM * 2);
    bf16* Kp   = (bf16*)alloc((size_t)MROWS * DM * 2);
    bf16* Vp   = (bf16*)alloc((size_t)MROWS * DM * 2);
    bf16* Ab   = (bf16*)alloc((size_t)MROWS * DM * 2);
    float* KVTp = (float*)alloc((size_t)BHEADS * KV_S * KVT_STRIDE * 4);
    bf16* KVT  = (bf16*)alloc((size_t)BHEADS * 4096 * 2);
    float* Ksum = (float*)alloc((size_t)BHEADS * 64 * 4);
    float* Z    = (float*)alloc((size_t)BHEADS * LSEQ * 4);

    // 1. casts (one launch for all 7 tensors)
    CastArgs ca;
    ca.s[0] = q;  ca.s[1] = k;  ca.s[2] = v;  ca.s[3] = wq; ca.s[4] = wk; ca.s[5] = wv; ca.s[6] = wo;
    ca.d[0] = qb; ca.d[1] = kb; ca.d[2] = vb; ca.d[3] = wqb; ca.d[4] = wkb; ca.d[5] = wvb; ca.d[6] = wob;
    const int nb_big = MROWS * DM / 4 / 256, nb_w = DM * DM / 4 / 256;
    ca.nblk[0] = nb_big; ca.nblk[1] = nb_big; ca.nblk[2] = nb_big;
    ca.nblk[3] = nb_w; ca.nblk[4] = nb_w; ca.nblk[5] = nb_w; ca.nblk[6] = nb_w;
    cast_all<<<dim3(nb_big, 1, 7), 256, 0, stream>>>(ca);

    // 2. projections (fused fmap for Q,K)
    GemmArgs pa;
    pa.A[0] = qb;  pa.A[1] = kb;  pa.A[2] = vb;
    pa.B[0] = wqb; pa.B[1] = wkb; pa.B[2] = wvb;
    pa.C[0] = Qp;  pa.C[1] = Kp;  pa.C[2] = Vp;
    pa.mode[0] = 1; pa.mode[1] = 1; pa.mode[2] = 0;
    pa.Ndim = DM; pa.Kdim = DM;
    gemm_nt<<<dim3(DM / 128, MROWS / 128, 3), 256, 0, stream>>>(pa);

    // 3. KV^T + Ksum
    kv_partial<<<dim3(BHEADS, KV_S), 256, 0, stream>>>(Kp, Vp, KVTp);
    kv_reduce<<<dim3(BHEADS, (KVT_STRIDE + 255) / 256), 256, 0, stream>>>(KVTp, KVT, Ksum);

    // 4. Z
    z_kernel<<<dim3(BHEADS, LSEQ / 256), 256, 0, stream>>>(Qp, Ksum, Z);

    // 5. attention output (Z fused into epilogue)
    attn_out<<<dim3(LSEQ / 128, BHEADS), 256, 0, stream>>>(Qp, KVT, Z, Ab);

    // 6. output projection -> fp32 d_out
    GemmArgs fa;
    fa.A[0] = Ab; fa.A[1] = nullptr; fa.A[2] = nullptr;
    fa.B[0] = wob; fa.B[1] = nullptr; fa.B[2] = nullptr;
    fa.C[0] = d_out; fa.C[1] = nullptr; fa.C[2] = nullptr;
    fa.mode[0] = 2; fa.mode[1] = 0; fa.mode[2] = 0;
    fa.Ndim = DM; fa.Kdim = DM;
    gemm_nt<<<dim3(DM / 128, MROWS / 128, 1), 256, 0, stream>>>(fa);
}

// Round 3
// 299.632 us; speedup vs baseline: 1.0959x; 1.0509x over previous
//
#include <hip/hip_runtime.h>
#include <cstdint>
#include <cstddef>

typedef __bf16 bf16;
typedef __bf16 bf16x8 __attribute__((ext_vector_type(8)));
typedef __bf16 bf16x4 __attribute__((ext_vector_type(4)));
typedef float  f32x4  __attribute__((ext_vector_type(4)));

#define DM     1024
#define MROWS  8192   // B*L
#define LSEQ   2048
#define NBATCH 4
#define NHEAD  16
#define BHEADS 64     // B*H
#define KV_S   8      // L-splits for KV partial reduction
#define KVT_STRIDE 4160  // 64*64 KV^T + 64 ksum

// async global->LDS, 16B per lane, LDS dest = wave-uniform base + lane*16
__device__ __forceinline__ void async16(const void* g, void* l) {
    __builtin_amdgcn_global_load_lds(
        (const __attribute__((address_space(1))) void*)g,
        (__attribute__((address_space(3))) void*)l, 16, 0, 0);
}

// ---------------- merged cast kernel (fp32 -> bf16), 7 tensors ----------------
struct CastArgs {
    const float* s[7];
    bf16*        d[7];
    int          nblk[7];
};

__global__ __launch_bounds__(256) void cast_all(CastArgs a) {
    const int z = blockIdx.z;
    if ((int)blockIdx.x >= a.nblk[z]) return;
    const int i = blockIdx.x * 256 + threadIdx.x;
    float4 f = ((const float4*)a.s[z])[i];
    bf16x4 o; o[0] = (bf16)f.x; o[1] = (bf16)f.y; o[2] = (bf16)f.z; o[3] = (bf16)f.w;
    ((bf16x4*)a.d[z])[i] = o;
}

// ---------------- batched NT GEMM: C = A @ B^T ----------------
// A [M x K] bf16 row-major, B [N x K] bf16 row-major. BK=64, XOR-swizzled LDS.
// Grid fixed (8, 64, z). XCD swizzle: blocks sharing an A row-stripe map to the
// same XCD so the stripe + full B (2MB+2MB) fit that XCD's 4MB L2.
// mode 0: store bf16; mode 1: fmap (elu+1) then store bf16; mode 2: store fp32
struct GemmArgs {
    const bf16* A[3];
    const bf16* B[3];
    void*       C[3];
    int         mode[3];
    int         Ndim;
    int         Kdim;
};

__global__ __launch_bounds__(256) void gemm_nt(GemmArgs args) {
    const int z = blockIdx.z;
    const bf16* __restrict__ A  = args.A[z];
    const bf16* __restrict__ Bm = args.B[z];
    void* Cp = args.C[z];
    const int mode = args.mode[z];
    const int N = args.Ndim, K = args.Kdim;

    __shared__ __attribute__((aligned(16))) bf16 sA[128 * 64];
    __shared__ __attribute__((aligned(16))) bf16 sB[128 * 64];

    const int tid  = threadIdx.x;
    const int wave = tid >> 6;
    const int lane = tid & 63;
    const int wm = wave >> 1, wn = wave & 1;

    // XCD-aware swizzle (grid x=8, y=64): all 8 col-blocks of a row-stripe get
    // the same (flat mod 8) => same XCD under round-robin dispatch.
    const int fb = blockIdx.x + 8 * (int)blockIdx.y;   // 0..511
    const int bx = (fb >> 3) & 7;
    const int by = (fb & 7) * 8 + (fb >> 6);
    const int row0 = by * 128;
    const int col0 = bx * 128;

    // staging: 8 rows x 8 chunks (16B) per issue per wave; chunk XOR-swizzled by row&7
    const int rr = lane >> 3;          // row within 8-row issue
    const int cc = lane & 7;           // 16B chunk index
    const int csw = ((cc ^ rr) * 8);   // swizzled element offset within 64-col row
    const bf16* gA = A  + (size_t)(row0 + wave * 32 + rr) * K + csw;
    const bf16* gB = Bm + (size_t)(col0 + wave * 32 + rr) * K + csw;

    f32x4 acc[4][4] = {};

    const int lr = lane & 15;
    const int qd = lane >> 4;
    const int swz = lr & 7;

    for (int k0 = 0; k0 < K; k0 += 64) {
        #pragma unroll
        for (int j = 0; j < 4; ++j) {
            async16(gA + k0 + (size_t)(j * 8) * K, &sA[(wave * 32 + j * 8) * 64]);
            async16(gB + k0 + (size_t)(j * 8) * K, &sB[(wave * 32 + j * 8) * 64]);
        }
        __syncthreads();

        #pragma unroll
        for (int ks = 0; ks < 2; ++ks) {
            bf16x8 af[4], bfr[4];
            #pragma unroll
            for (int mi = 0; mi < 4; ++mi)
                af[mi] = *(const bf16x8*)&sA[(wm * 64 + mi * 16 + lr) * 64 + (((ks * 4 + qd) ^ swz) * 8)];
            #pragma unroll
            for (int ni = 0; ni < 4; ++ni)
                bfr[ni] = *(const bf16x8*)&sB[(wn * 64 + ni * 16 + lr) * 64 + (((ks * 4 + qd) ^ swz) * 8)];
            #pragma unroll
            for (int mi = 0; mi < 4; ++mi)
                #pragma unroll
                for (int ni = 0; ni < 4; ++ni)
                    acc[mi][ni] = __builtin_amdgcn_mfma_f32_16x16x32_bf16(af[mi], bfr[ni], acc[mi][ni], 0, 0, 0);
        }
        __syncthreads();
    }

    #pragma unroll
    for (int mi = 0; mi < 4; ++mi) {
        #pragma unroll
        for (int ni = 0; ni < 4; ++ni) {
            #pragma unroll
            for (int r = 0; r < 4; ++r) {
                const int grow = row0 + wm * 64 + mi * 16 + qd * 4 + r;
                const int gcol = col0 + wn * 64 + ni * 16 + lr;
                float val = acc[mi][ni][r];
                if (mode == 1) val = (val > 0.f) ? (val + 1.f) : __expf(val);
                if (mode == 2) ((float*)Cp)[(size_t)grow * N + gcol] = val;
                else           ((bf16*)Cp)[(size_t)grow * N + gcol] = (bf16)val;
            }
        }
    }
}

// ---------------- KV^T partial: KVT[m][d] += V[n,m]*K[n,d], plus Ksum ----------------
__global__ __launch_bounds__(256) void kv_partial(const bf16* __restrict__ Kp,
                                                  const bf16* __restrict__ Vp,
                                                  float* __restrict__ KVTp) {
    const int bh = blockIdx.x, s = blockIdx.y;
    const int b = bh >> 4, h = bh & 15;
    const int tid = threadIdx.x;
    const int m  = tid & 63;   // KVT row (V column); for wave 0 also serves as d for ksum
    const int dg = tid >> 6;   // d-group (= wave index)

    __shared__ float sK[32][64];
    __shared__ float sV[32][64];

    float acc[16] = {};
    float ks = 0.f;

    const int rr = tid >> 3;          // 0..31 row
    const int cc = (tid & 7) * 8;     // element offset

    const size_t rowbase = (size_t)(b * LSEQ + s * 256) * DM + h * 64;

    for (int c = 0; c < 8; ++c) {
        {
            const size_t g = rowbase + (size_t)(c * 32 + rr) * DM + cc;
            bf16x8 k8 = *(const bf16x8*)&Kp[g];
            bf16x8 v8 = *(const bf16x8*)&Vp[g];
            float4 kf0 = {(float)k8[0], (float)k8[1], (float)k8[2], (float)k8[3]};
            float4 kf1 = {(float)k8[4], (float)k8[5], (float)k8[6], (float)k8[7]};
            float4 vf0 = {(float)v8[0], (float)v8[1], (float)v8[2], (float)v8[3]};
            float4 vf1 = {(float)v8[4], (float)v8[5], (float)v8[6], (float)v8[7]};
            *(float4*)&sK[rr][cc]     = kf0;
            *(float4*)&sK[rr][cc + 4] = kf1;
            *(float4*)&sV[rr][cc]     = vf0;
            *(float4*)&sV[rr][cc + 4] = vf1;
        }
        __syncthreads();
        #pragma unroll 4
        for (int n = 0; n < 32; ++n) {
            const float vv = sV[n][m];
            const float4* pk = (const float4*)&sK[n][dg * 16];
            #pragma unroll
            for (int t4 = 0; t4 < 4; ++t4) {
                float4 kk = pk[t4];
                acc[t4 * 4 + 0] += vv * kk.x;
                acc[t4 * 4 + 1] += vv * kk.y;
                acc[t4 * 4 + 2] += vv * kk.z;
                acc[t4 * 4 + 3] += vv * kk.w;
            }
            if (dg == 0) ks += sK[n][m];
        }
        __syncthreads();
    }

    float* outp = &KVTp[(size_t)(bh * KV_S + s) * KVT_STRIDE];
    #pragma unroll
    for (int t4 = 0; t4 < 4; ++t4) {
        float4 o = {acc[t4 * 4 + 0], acc[t4 * 4 + 1], acc[t4 * 4 + 2], acc[t4 * 4 + 3]};
        *(float4*)&outp[m * 64 + dg * 16 + t4 * 4] = o;
    }
    if (dg == 0) outp[4096 + m] = ks;
}

// parallel reduce: grid (BHEADS, 17)
__global__ __launch_bounds__(256) void kv_reduce(const float* __restrict__ KVTp,
                                                 bf16* __restrict__ KVT,
                                                 float* __restrict__ Ksum) {
    const int bh = blockIdx.x;
    const int idx = blockIdx.y * 256 + threadIdx.x;
    if (idx >= KVT_STRIDE) return;
    float s = 0.f;
    #pragma unroll
    for (int p = 0; p < KV_S; ++p) s += KVTp[(size_t)(bh * KV_S + p) * KVT_STRIDE + idx];
    if (idx < 4096) KVT[(size_t)bh * 4096 + idx] = (bf16)s;
    else            Ksum[bh * 64 + (idx - 4096)] = s;
}

// ---------------- attn out: A[n, h*64+m] = Z[n] * sum_d Q[n,d]*KVT[m,d] (MFMA NT) ----------------
// Z computed in-kernel: Z[n] = 1/(dot(Q[n,:], Ksum) + eps) via 2-lanes-per-row dot + shfl.
__global__ __launch_bounds__(256) void attn_out(const bf16* __restrict__ Qp,
                                                const bf16* __restrict__ KVT,
                                                const float* __restrict__ Ksum,
                                                bf16* __restrict__ Ab) {
    const int bh = blockIdx.y;
    const int b = bh >> 4, h = bh & 15;
    const int row0 = blockIdx.x * 128;
    const int tid = threadIdx.x, wave = tid >> 6, lane = tid & 63;

    __shared__ __attribute__((aligned(16))) bf16 sQ[128 * 64];
    __shared__ __attribute__((aligned(16))) bf16 sKV[64 * 64];
    __shared__ float sKs[64];

    // staging with XOR swizzle (chunk ^= row&7 on the global side)
    const int rr8 = lane >> 3;
    const int cc8 = lane & 7;
    const int csw = ((cc8 ^ rr8) * 8);

    const bf16* qbase = &Qp[(size_t)(b * LSEQ + row0) * DM + h * 64];
    #pragma unroll
    for (int j = 0; j < 4; ++j) {   // 8 rows per issue
        const int r0 = wave * 32 + j * 8;
        async16(qbase + (size_t)(r0 + rr8) * DM + csw, &sQ[r0 * 64]);
    }
    const bf16* kvbase = &KVT[(size_t)bh * 4096];
    #pragma unroll
    for (int j = 0; j < 2; ++j) {
        const int r0 = wave * 16 + j * 8;
        async16(kvbase + (r0 + rr8) * 64 + csw, &sKV[r0 * 64]);
    }
    if (tid < 64) sKs[tid] = Ksum[bh * 64 + tid];
    __syncthreads();

    // Z: lane pair (2 lanes per row) dots Q row with Ksum
    const int zrow = lane >> 1;        // 0..31 within wave
    const int dh = lane & 1;           // which 32-dim half
    float zacc = 0.f;
    {
        const bf16* qr = &sQ[(wave * 32 + zrow) * 64];
        #pragma unroll
        for (int c = 0; c < 4; ++c) {
            const int chunk = dh * 4 + c;
            bf16x8 q8 = *(const bf16x8*)&qr[(chunk ^ (zrow & 7)) * 8];
            const float* ksp = &sKs[chunk * 8];
            #pragma unroll
            for (int j = 0; j < 8; ++j) zacc += (float)q8[j] * ksp[j];
        }
    }
    zacc += __shfl_xor(zacc, 1, 64);
    const float zinv = 1.0f / (zacc + 1e-8f);

    f32x4 acc[2][4] = {};
    const int lr = lane & 15, qd = lane >> 4;
    const int swz = lr & 7;
    #pragma unroll
    for (int ks = 0; ks < 2; ++ks) {
        bf16x8 af[2], bfr[4];
        #pragma unroll
        for (int mi = 0; mi < 2; ++mi)
            af[mi] = *(const bf16x8*)&sQ[(wave * 32 + mi * 16 + lr) * 64 + (((ks * 4 + qd) ^ swz) * 8)];
        #pragma unroll
        for (int ni = 0; ni < 4; ++ni)
            bfr[ni] = *(const bf16x8*)&sKV[(ni * 16 + lr) * 64 + (((ks * 4 + qd) ^ swz) * 8)];
        #pragma unroll
        for (int mi = 0; mi < 2; ++mi)
            #pragma unroll
            for (int ni = 0; ni < 4; ++ni)
                acc[mi][ni] = __builtin_amdgcn_mfma_f32_16x16x32_bf16(af[mi], bfr[ni], acc[mi][ni], 0, 0, 0);
    }

    #pragma unroll
    for (int mi = 0; mi < 2; ++mi) {
        #pragma unroll
        for (int rr = 0; rr < 4; ++rr) {
            const int rlocal = mi * 16 + qd * 4 + rr;          // 0..31 within wave
            const float zv = __shfl(zinv, rlocal * 2, 64);
            const int nrow = row0 + wave * 32 + rlocal;
            #pragma unroll
            for (int ni = 0; ni < 4; ++ni)
                Ab[(size_t)(b * LSEQ + nrow) * DM + h * 64 + ni * 16 + lr] =
                    (bf16)(acc[mi][ni][rr] * zv);
        }
    }
}

extern "C" void kernel_launch(void* const* d_in, const int* in_sizes, int n_in,
                              void* d_out, int out_size, void* d_ws, size_t ws_size,
                              hipStream_t stream) {
    const float* q  = (const float*)d_in[0];
    const float* k  = (const float*)d_in[1];
    const float* v  = (const float*)d_in[2];
    // d_in[3] = mask (all-ones, unused in linear branch)
    const float* wq = (const float*)d_in[4];
    const float* wk = (const float*)d_in[5];
    const float* wv = (const float*)d_in[6];
    const float* wo = (const float*)d_in[7];

    char* ws = (char*)d_ws;
    size_t off = 0;
    auto alloc = [&](size_t bytes) -> void* {
        void* p = ws + off;
        off += (bytes + 255) & ~(size_t)255;
        return p;
    };

    bf16* qb   = (bf16*)alloc((size_t)MROWS * DM * 2);
    bf16* kb   = (bf16*)alloc((size_t)MROWS * DM * 2);
    bf16* vb   = (bf16*)alloc((size_t)MROWS * DM * 2);
    bf16* wqb  = (bf16*)alloc((size_t)DM * DM * 2);
    bf16* wkb  = (bf16*)alloc((size_t)DM * DM * 2);
    bf16* wvb  = (bf16*)alloc((size_t)DM * DM * 2);
    bf16* wob  = (bf16*)alloc((size_t)DM * DM * 2);
    bf16* Qp   = (bf16*)alloc((size_t)MROWS * DM * 2);
    bf16* Kp   = (bf16*)alloc((size_t)MROWS * DM * 2);
    bf16* Vp   = (bf16*)alloc((size_t)MROWS * DM * 2);
    bf16* Ab   = (bf16*)alloc((size_t)MROWS * DM * 2);
    float* KVTp = (float*)alloc((size_t)BHEADS * KV_S * KVT_STRIDE * 4);
    bf16* KVT  = (bf16*)alloc((size_t)BHEADS * 4096 * 2);
    float* Ksum = (float*)alloc((size_t)BHEADS * 64 * 4);

    // 1. casts (one launch for all 7 tensors)
    CastArgs ca;
    ca.s[0] = q;  ca.s[1] = k;  ca.s[2] = v;  ca.s[3] = wq; ca.s[4] = wk; ca.s[5] = wv; ca.s[6] = wo;
    ca.d[0] = qb; ca.d[1] = kb; ca.d[2] = vb; ca.d[3] = wqb; ca.d[4] = wkb; ca.d[5] = wvb; ca.d[6] = wob;
    const int nb_big = MROWS * DM / 4 / 256, nb_w = DM * DM / 4 / 256;
    ca.nblk[0] = nb_big; ca.nblk[1] = nb_big; ca.nblk[2] = nb_big;
    ca.nblk[3] = nb_w; ca.nblk[4] = nb_w; ca.nblk[5] = nb_w; ca.nblk[6] = nb_w;
    cast_all<<<dim3(nb_big, 1, 7), 256, 0, stream>>>(ca);

    // 2. projections (fused fmap for Q,K)
    GemmArgs pa;
    pa.A[0] = qb;  pa.A[1] = kb;  pa.A[2] = vb;
    pa.B[0] = wqb; pa.B[1] = wkb; pa.B[2] = wvb;
    pa.C[0] = Qp;  pa.C[1] = Kp;  pa.C[2] = Vp;
    pa.mode[0] = 1; pa.mode[1] = 1; pa.mode[2] = 0;
    pa.Ndim = DM; pa.Kdim = DM;
    gemm_nt<<<dim3(DM / 128, MROWS / 128, 3), 256, 0, stream>>>(pa);

    // 3. KV^T + Ksum
    kv_partial<<<dim3(BHEADS, KV_S), 256, 0, stream>>>(Kp, Vp, KVTp);
    kv_reduce<<<dim3(BHEADS, (KVT_STRIDE + 255) / 256), 256, 0, stream>>>(KVTp, KVT, Ksum);

    // 4. attention output (Z computed in-kernel, fused into epilogue)
    attn_out<<<dim3(LSEQ / 128, BHEADS), 256, 0, stream>>>(Qp, KVT, Ksum, Ab);

    // 5. output projection -> fp32 d_out
    GemmArgs fa;
    fa.A[0] = Ab; fa.A[1] = nullptr; fa.A[2] = nullptr;
    fa.B[0] = wob; fa.B[1] = nullptr; fa.B[2] = nullptr;
    fa.C[0] = d_out; fa.C[1] = nullptr; fa.C[2] = nullptr;
    fa.mode[0] = 2; fa.mode[1] = 0; fa.mode[2] = 0;
    fa.Ndim = DM; fa.Kdim = DM;
    gemm_nt<<<dim3(DM / 128, MROWS / 128, 1), 256, 0, stream>>>(fa);
}

// Round 4
// 264.697 us; speedup vs baseline: 1.2406x; 1.1320x over previous
//
#include <hip/hip_runtime.h>
#include <cstdint>
#include <cstddef>

typedef __bf16 bf16;
typedef __bf16 bf16x8 __attribute__((ext_vector_type(8)));
typedef __bf16 bf16x4 __attribute__((ext_vector_type(4)));
typedef float  f32x4  __attribute__((ext_vector_type(4)));

#define DM     1024
#define MROWS  8192   // B*L
#define LSEQ   2048
#define NBATCH 4
#define NHEAD  16
#define BHEADS 64     // B*H
#define KV_S   8      // L-splits for KV partial reduction
#define KVT_STRIDE 4160  // 64*64 KV^T + 64 ksum

// async global->LDS, 16B per lane, LDS dest = wave-uniform base + lane*16
__device__ __forceinline__ void async16(const void* g, void* l) {
    __builtin_amdgcn_global_load_lds(
        (const __attribute__((address_space(1))) void*)g,
        (__attribute__((address_space(3))) void*)l, 16, 0, 0);
}

// ---------------- merged cast kernel (fp32 -> bf16), 7 tensors ----------------
struct CastArgs {
    const float* s[7];
    bf16*        d[7];
    int          nblk[7];
};

__global__ __launch_bounds__(256) void cast_all(CastArgs a) {
    const int z = blockIdx.z;
    if ((int)blockIdx.x >= a.nblk[z]) return;
    const int i = blockIdx.x * 256 + threadIdx.x;
    float4 f = ((const float4*)a.s[z])[i];
    bf16x4 o; o[0] = (bf16)f.x; o[1] = (bf16)f.y; o[2] = (bf16)f.z; o[3] = (bf16)f.w;
    ((bf16x4*)a.d[z])[i] = o;
}

// ---------------- batched NT GEMM: C = A @ B^T ----------------
// A [M x K] bf16 row-major, B [N x K] bf16 row-major. BK=64, XOR-swizzled LDS.
// Grid fixed (8, 64, z), XCD swizzle keeps a row-stripe + B inside one XCD L2.
// mode 1: fmap (elu+1), store bf16 row-major
// mode 3: store bf16 transposed per-head  dst[((b*16+h)*64+d)*2048 + n]
// mode 4: fmap + transposed per-head
struct GemmArgs {
    const bf16* A[3];
    const bf16* B[3];
    void*       C[3];
    int         mode[3];
};

__global__ __launch_bounds__(256) void gemm_nt(GemmArgs args) {
    const int z = blockIdx.z;
    const bf16* __restrict__ A  = args.A[z];
    const bf16* __restrict__ Bm = args.B[z];
    void* Cp = args.C[z];
    const int mode = args.mode[z];
    const int K = DM;

    __shared__ __attribute__((aligned(16))) bf16 sA[128 * 64];
    __shared__ __attribute__((aligned(16))) bf16 sB[128 * 64];

    const int tid  = threadIdx.x;
    const int wave = tid >> 6;
    const int lane = tid & 63;
    const int wm = wave >> 1, wn = wave & 1;

    // XCD-aware swizzle (grid x=8, y=64)
    const int fb = blockIdx.x + 8 * (int)blockIdx.y;   // 0..511
    const int bx = (fb >> 3) & 7;
    const int by = (fb & 7) * 8 + (fb >> 6);
    const int row0 = by * 128;
    const int col0 = bx * 128;

    // staging: 8 rows x 8 chunks (16B) per issue; chunk XOR-swizzled by row&7
    const int rr = lane >> 3;
    const int cc = lane & 7;
    const int csw = ((cc ^ rr) * 8);
    const bf16* gA = A  + (size_t)(row0 + wave * 32 + rr) * K + csw;
    const bf16* gB = Bm + (size_t)(col0 + wave * 32 + rr) * K + csw;

    f32x4 acc[4][4] = {};

    const int lr = lane & 15;
    const int qd = lane >> 4;
    const int swz = lr & 7;

    for (int k0 = 0; k0 < K; k0 += 64) {
        #pragma unroll
        for (int j = 0; j < 4; ++j) {
            async16(gA + k0 + (size_t)(j * 8) * K, &sA[(wave * 32 + j * 8) * 64]);
            async16(gB + k0 + (size_t)(j * 8) * K, &sB[(wave * 32 + j * 8) * 64]);
        }
        __syncthreads();

        #pragma unroll
        for (int ks = 0; ks < 2; ++ks) {
            bf16x8 af[4], bfr[4];
            #pragma unroll
            for (int mi = 0; mi < 4; ++mi)
                af[mi] = *(const bf16x8*)&sA[(wm * 64 + mi * 16 + lr) * 64 + (((ks * 4 + qd) ^ swz) * 8)];
            #pragma unroll
            for (int ni = 0; ni < 4; ++ni)
                bfr[ni] = *(const bf16x8*)&sB[(wn * 64 + ni * 16 + lr) * 64 + (((ks * 4 + qd) ^ swz) * 8)];
            #pragma unroll
            for (int mi = 0; mi < 4; ++mi)
                #pragma unroll
                for (int ni = 0; ni < 4; ++ni)
                    acc[mi][ni] = __builtin_amdgcn_mfma_f32_16x16x32_bf16(af[mi], bfr[ni], acc[mi][ni], 0, 0, 0);
        }
        __syncthreads();
    }

    if (mode >= 3) {
        // transposed per-head: 4 row-consecutive acc values -> one 8B store
        #pragma unroll
        for (int mi = 0; mi < 4; ++mi) {
            const int grow0 = row0 + wm * 64 + mi * 16 + qd * 4;
            const int b  = grow0 >> 11;
            const int n0 = grow0 & 2047;
            #pragma unroll
            for (int ni = 0; ni < 4; ++ni) {
                const int gcol = col0 + wn * 64 + ni * 16 + lr;
                const int h = gcol >> 6;
                const int d = gcol & 63;
                bf16x4 o;
                #pragma unroll
                for (int r = 0; r < 4; ++r) {
                    float val = acc[mi][ni][r];
                    if (mode == 4) val = (val > 0.f) ? (val + 1.f) : __expf(val);
                    o[r] = (bf16)val;
                }
                *(bf16x4*)&((bf16*)Cp)[(size_t)((b * 16 + h) * 64 + d) * 2048 + n0] = o;
            }
        }
    } else {
        #pragma unroll
        for (int mi = 0; mi < 4; ++mi) {
            #pragma unroll
            for (int ni = 0; ni < 4; ++ni) {
                #pragma unroll
                for (int r = 0; r < 4; ++r) {
                    const int grow = row0 + wm * 64 + mi * 16 + qd * 4 + r;
                    const int gcol = col0 + wn * 64 + ni * 16 + lr;
                    float val = acc[mi][ni][r];
                    if (mode == 1) val = (val > 0.f) ? (val + 1.f) : __expf(val);
                    ((bf16*)Cp)[(size_t)grow * DM + gcol] = (bf16)val;
                }
            }
        }
    }
}

// ---------------- final GEMM: d_out = Ab @ wob^T, fp32 out, 128x64 tiles ----------------
__global__ __launch_bounds__(256) void gemm_fin(const bf16* __restrict__ A,
                                                const bf16* __restrict__ Bm,
                                                float* __restrict__ C) {
    const int K = DM;
    __shared__ __attribute__((aligned(16))) bf16 sA[128 * 64];
    __shared__ __attribute__((aligned(16))) bf16 sB[64 * 64];

    const int tid  = threadIdx.x;
    const int wave = tid >> 6;
    const int lane = tid & 63;
    const int wm = wave >> 1, wn = wave & 1;

    // XCD swizzle (grid x=16, y=64): each XCD owns 8 A row-stripes (2MB) + B (2MB)
    const int fb = blockIdx.x + 16 * (int)blockIdx.y;  // 0..1023
    const int xcd = fb & 7;
    const int g = fb >> 3;
    const int bx = g & 15;
    const int by = xcd * 8 + (g >> 4);
    const int row0 = by * 128;
    const int col0 = bx * 64;

    const int rr = lane >> 3;
    const int cc = lane & 7;
    const int csw = ((cc ^ rr) * 8);
    const bf16* gA = A  + (size_t)(row0 + wave * 32 + rr) * K + csw;
    const bf16* gB = Bm + (size_t)(col0 + wave * 16 + rr) * K + csw;

    f32x4 acc[4][2] = {};

    const int lr = lane & 15;
    const int qd = lane >> 4;
    const int swz = lr & 7;

    for (int k0 = 0; k0 < K; k0 += 64) {
        #pragma unroll
        for (int j = 0; j < 4; ++j)
            async16(gA + k0 + (size_t)(j * 8) * K, &sA[(wave * 32 + j * 8) * 64]);
        #pragma unroll
        for (int j = 0; j < 2; ++j)
            async16(gB + k0 + (size_t)(j * 8) * K, &sB[(wave * 16 + j * 8) * 64]);
        __syncthreads();

        #pragma unroll
        for (int ks = 0; ks < 2; ++ks) {
            bf16x8 af[4], bfr[2];
            #pragma unroll
            for (int mi = 0; mi < 4; ++mi)
                af[mi] = *(const bf16x8*)&sA[(wm * 64 + mi * 16 + lr) * 64 + (((ks * 4 + qd) ^ swz) * 8)];
            #pragma unroll
            for (int ni = 0; ni < 2; ++ni)
                bfr[ni] = *(const bf16x8*)&sB[(wn * 32 + ni * 16 + lr) * 64 + (((ks * 4 + qd) ^ swz) * 8)];
            #pragma unroll
            for (int mi = 0; mi < 4; ++mi)
                #pragma unroll
                for (int ni = 0; ni < 2; ++ni)
                    acc[mi][ni] = __builtin_amdgcn_mfma_f32_16x16x32_bf16(af[mi], bfr[ni], acc[mi][ni], 0, 0, 0);
        }
        __syncthreads();
    }

    #pragma unroll
    for (int mi = 0; mi < 4; ++mi)
        #pragma unroll
        for (int ni = 0; ni < 2; ++ni)
            #pragma unroll
            for (int r = 0; r < 4; ++r) {
                const int grow = row0 + wm * 64 + mi * 16 + qd * 4 + r;
                const int gcol = col0 + wn * 32 + ni * 16 + lr;
                C[(size_t)grow * DM + gcol] = acc[mi][ni][r];
            }
}

// ---------------- KV^T via MFMA: KVT[m][d] = sum_n V[n][m]*K[n][d], plus Ksum ----------------
// Inputs are per-head transposed: KpT/VpT [bh][64][2048] bf16 (contraction-major rows).
__global__ __launch_bounds__(256) void kv_mfma(const bf16* __restrict__ KpT,
                                               const bf16* __restrict__ VpT,
                                               float* __restrict__ KVTp) {
    const int bh = blockIdx.x, s = blockIdx.y;
    const int tid = threadIdx.x, wave = tid >> 6, lane = tid & 63;

    __shared__ __attribute__((aligned(16))) bf16 sVT[64 * 256];
    __shared__ __attribute__((aligned(16))) bf16 sKT[64 * 256];

    // stage 64 rows x 256 n per tensor; 2 rows per issue, XOR chunk swizzle by row&7
    const int dd = lane >> 5;
    const int c  = lane & 31;
    #pragma unroll
    for (int j = 0; j < 8; ++j) {
        const int i2 = (wave * 8 + j) * 2;
        const int r  = i2 + dd;
        const int cs = (c ^ (r & 7)) * 8;
        const size_t gofs = (size_t)(bh * 64 + r) * 2048 + s * 256 + cs;
        async16(VpT + gofs, &sVT[i2 * 256]);
        async16(KpT + gofs, &sKT[i2 * 256]);
    }
    __syncthreads();

    const int lr = lane & 15, qd = lane >> 4;
    f32x4 acc[4] = {};
    const int rA = wave * 16 + lr;
    #pragma unroll
    for (int k0 = 0; k0 < 8; ++k0) {
        const int ch = k0 * 4 + qd;
        bf16x8 a = *(const bf16x8*)&sVT[rA * 256 + ((ch ^ (rA & 7)) * 8)];
        #pragma unroll
        for (int ni = 0; ni < 4; ++ni) {
            const int rB = ni * 16 + lr;
            bf16x8 b = *(const bf16x8*)&sKT[rB * 256 + ((ch ^ (rB & 7)) * 8)];
            acc[ni] = __builtin_amdgcn_mfma_f32_16x16x32_bf16(a, b, acc[ni], 0, 0, 0);
        }
    }

    float* outp = &KVTp[(size_t)(bh * KV_S + s) * KVT_STRIDE];
    #pragma unroll
    for (int ni = 0; ni < 4; ++ni)
        #pragma unroll
        for (int r = 0; r < 4; ++r)
            outp[(wave * 16 + qd * 4 + r) * 64 + ni * 16 + lr] = acc[ni][r];

    if (wave == 0) {   // partial Ksum: lane d sums its KpT row chunk
        float ks = 0.f;
        #pragma unroll
        for (int c2 = 0; c2 < 32; ++c2) {
            bf16x8 kk = *(const bf16x8*)&sKT[lane * 256 + ((c2 ^ (lane & 7)) * 8)];
            #pragma unroll
            for (int j = 0; j < 8; ++j) ks += (float)kk[j];
        }
        outp[4096 + lane] = ks;
    }
}

// parallel reduce: grid (BHEADS, 17)
__global__ __launch_bounds__(256) void kv_reduce(const float* __restrict__ KVTp,
                                                 bf16* __restrict__ KVT,
                                                 float* __restrict__ Ksum) {
    const int bh = blockIdx.x;
    const int idx = blockIdx.y * 256 + threadIdx.x;
    if (idx >= KVT_STRIDE) return;
    float s = 0.f;
    #pragma unroll
    for (int p = 0; p < KV_S; ++p) s += KVTp[(size_t)(bh * KV_S + p) * KVT_STRIDE + idx];
    if (idx < 4096) KVT[(size_t)bh * 4096 + idx] = (bf16)s;
    else            Ksum[bh * 64 + (idx - 4096)] = s;
}

// ---------------- attn out: A[n, h*64+m] = Z[n] * sum_d Q[n,d]*KVT[m,d] (MFMA NT) ----------------
__global__ __launch_bounds__(256) void attn_out(const bf16* __restrict__ Qp,
                                                const bf16* __restrict__ KVT,
                                                const float* __restrict__ Ksum,
                                                bf16* __restrict__ Ab) {
    const int bh = blockIdx.y;
    const int b = bh >> 4, h = bh & 15;
    const int row0 = blockIdx.x * 128;
    const int tid = threadIdx.x, wave = tid >> 6, lane = tid & 63;

    __shared__ __attribute__((aligned(16))) bf16 sQ[128 * 64];
    __shared__ __attribute__((aligned(16))) bf16 sKV[64 * 64];
    __shared__ float sKs[64];

    const int rr8 = lane >> 3;
    const int cc8 = lane & 7;
    const int csw = ((cc8 ^ rr8) * 8);

    const bf16* qbase = &Qp[(size_t)(b * LSEQ + row0) * DM + h * 64];
    #pragma unroll
    for (int j = 0; j < 4; ++j) {
        const int r0 = wave * 32 + j * 8;
        async16(qbase + (size_t)(r0 + rr8) * DM + csw, &sQ[r0 * 64]);
    }
    const bf16* kvbase = &KVT[(size_t)bh * 4096];
    #pragma unroll
    for (int j = 0; j < 2; ++j) {
        const int r0 = wave * 16 + j * 8;
        async16(kvbase + (r0 + rr8) * 64 + csw, &sKV[r0 * 64]);
    }
    if (tid < 64) sKs[tid] = Ksum[bh * 64 + tid];
    __syncthreads();

    // Z: lane pair dots Q row with Ksum
    const int zrow = lane >> 1;
    const int dh = lane & 1;
    float zacc = 0.f;
    {
        const bf16* qr = &sQ[(wave * 32 + zrow) * 64];
        #pragma unroll
        for (int c = 0; c < 4; ++c) {
            const int chunk = dh * 4 + c;
            bf16x8 q8 = *(const bf16x8*)&qr[(chunk ^ (zrow & 7)) * 8];
            const float* ksp = &sKs[chunk * 8];
            #pragma unroll
            for (int j = 0; j < 8; ++j) zacc += (float)q8[j] * ksp[j];
        }
    }
    zacc += __shfl_xor(zacc, 1, 64);
    const float zinv = 1.0f / (zacc + 1e-8f);

    f32x4 acc[2][4] = {};
    const int lr = lane & 15, qd = lane >> 4;
    const int swz = lr & 7;
    #pragma unroll
    for (int ks = 0; ks < 2; ++ks) {
        bf16x8 af[2], bfr[4];
        #pragma unroll
        for (int mi = 0; mi < 2; ++mi)
            af[mi] = *(const bf16x8*)&sQ[(wave * 32 + mi * 16 + lr) * 64 + (((ks * 4 + qd) ^ swz) * 8)];
        #pragma unroll
        for (int ni = 0; ni < 4; ++ni)
            bfr[ni] = *(const bf16x8*)&sKV[(ni * 16 + lr) * 64 + (((ks * 4 + qd) ^ swz) * 8)];
        #pragma unroll
        for (int mi = 0; mi < 2; ++mi)
            #pragma unroll
            for (int ni = 0; ni < 4; ++ni)
                acc[mi][ni] = __builtin_amdgcn_mfma_f32_16x16x32_bf16(af[mi], bfr[ni], acc[mi][ni], 0, 0, 0);
    }

    #pragma unroll
    for (int mi = 0; mi < 2; ++mi) {
        #pragma unroll
        for (int rr = 0; rr < 4; ++rr) {
            const int rlocal = mi * 16 + qd * 4 + rr;
            const float zv = __shfl(zinv, rlocal * 2, 64);
            const int nrow = row0 + wave * 32 + rlocal;
            #pragma unroll
            for (int ni = 0; ni < 4; ++ni)
                Ab[(size_t)(b * LSEQ + nrow) * DM + h * 64 + ni * 16 + lr] =
                    (bf16)(acc[mi][ni][rr] * zv);
        }
    }
}

extern "C" void kernel_launch(void* const* d_in, const int* in_sizes, int n_in,
                              void* d_out, int out_size, void* d_ws, size_t ws_size,
                              hipStream_t stream) {
    const float* q  = (const float*)d_in[0];
    const float* k  = (const float*)d_in[1];
    const float* v  = (const float*)d_in[2];
    // d_in[3] = mask (all-ones, unused in linear branch)
    const float* wq = (const float*)d_in[4];
    const float* wk = (const float*)d_in[5];
    const float* wv = (const float*)d_in[6];
    const float* wo = (const float*)d_in[7];

    char* ws = (char*)d_ws;
    size_t off = 0;
    auto alloc = [&](size_t bytes) -> void* {
        void* p = ws + off;
        off += (bytes + 255) & ~(size_t)255;
        return p;
    };

    bf16* qb   = (bf16*)alloc((size_t)MROWS * DM * 2);
    bf16* kb   = (bf16*)alloc((size_t)MROWS * DM * 2);
    bf16* vb   = (bf16*)alloc((size_t)MROWS * DM * 2);
    bf16* wqb  = (bf16*)alloc((size_t)DM * DM * 2);
    bf16* wkb  = (bf16*)alloc((size_t)DM * DM * 2);
    bf16* wvb  = (bf16*)alloc((size_t)DM * DM * 2);
    bf16* wob  = (bf16*)alloc((size_t)DM * DM * 2);
    bf16* Qp   = (bf16*)alloc((size_t)MROWS * DM * 2);   // row-major [B*L][1024]
    bf16* KpT  = (bf16*)alloc((size_t)MROWS * DM * 2);   // per-head T [bh][64][2048]
    bf16* VpT  = (bf16*)alloc((size_t)MROWS * DM * 2);   // per-head T [bh][64][2048]
    bf16* Ab   = (bf16*)alloc((size_t)MROWS * DM * 2);
    float* KVTp = (float*)alloc((size_t)BHEADS * KV_S * KVT_STRIDE * 4);
    bf16* KVT  = (bf16*)alloc((size_t)BHEADS * 4096 * 2);
    float* Ksum = (float*)alloc((size_t)BHEADS * 64 * 4);

    // 1. casts
    CastArgs ca;
    ca.s[0] = q;  ca.s[1] = k;  ca.s[2] = v;  ca.s[3] = wq; ca.s[4] = wk; ca.s[5] = wv; ca.s[6] = wo;
    ca.d[0] = qb; ca.d[1] = kb; ca.d[2] = vb; ca.d[3] = wqb; ca.d[4] = wkb; ca.d[5] = wvb; ca.d[6] = wob;
    const int nb_big = MROWS * DM / 4 / 256, nb_w = DM * DM / 4 / 256;
    ca.nblk[0] = nb_big; ca.nblk[1] = nb_big; ca.nblk[2] = nb_big;
    ca.nblk[3] = nb_w; ca.nblk[4] = nb_w; ca.nblk[5] = nb_w; ca.nblk[6] = nb_w;
    cast_all<<<dim3(nb_big, 1, 7), 256, 0, stream>>>(ca);

    // 2. projections: Q row-major+fmap, K transposed+fmap, V transposed
    GemmArgs pa;
    pa.A[0] = qb;  pa.A[1] = kb;  pa.A[2] = vb;
    pa.B[0] = wqb; pa.B[1] = wkb; pa.B[2] = wvb;
    pa.C[0] = Qp;  pa.C[1] = KpT; pa.C[2] = VpT;
    pa.mode[0] = 1; pa.mode[1] = 4; pa.mode[2] = 3;
    gemm_nt<<<dim3(DM / 128, MROWS / 128, 3), 256, 0, stream>>>(pa);

    // 3. KV^T + Ksum (MFMA) then reduce
    kv_mfma<<<dim3(BHEADS, KV_S), 256, 0, stream>>>(KpT, VpT, KVTp);
    kv_reduce<<<dim3(BHEADS, (KVT_STRIDE + 255) / 256), 256, 0, stream>>>(KVTp, KVT, Ksum);

    // 4. attention output (Z in-kernel)
    attn_out<<<dim3(LSEQ / 128, BHEADS), 256, 0, stream>>>(Qp, KVT, Ksum, Ab);

    // 5. output projection -> fp32 d_out (128x64 tiles, 1024 blocks)
    gemm_fin<<<dim3(DM / 64, MROWS / 128), 256, 0, stream>>>(Ab, wob, (float*)d_out);
}